// Round 11
// baseline (314.290 us; speedup 1.0000x reference)
//
#include <hip/hip_runtime.h>
#include <math.h>

namespace {
constexpr int DETN = 816;
constexpr int NVIEW = 720;
constexpr int NB = 8;
constexpr int IMGN = 512;
constexpr float PIXSZ = 0.5f;
constexpr float SID = 750.0f;
constexpr float SDD = 1250.0f;
constexpr float DBETA = 6.28318530717958647692f / 720.0f;

constexpr int XPAD2 = 1648;      // 407 left zeros + 816 data + 425 right zeros
constexpr int T = 16;            // outputs per thread
constexpr int TPR = DETN / T;    // 51 threads per row
constexpr int ROWSTRIDE = 1852;  // > F(1647)=1851, even
constexpr int NBB = 4;           // batches per filter block

constexpr int NSPLIT = 2;
constexpr int VH = NVIEW / NSPLIT;   // 360 views per half
constexpr int VP = VH / 2;           // 180 view-pairs

typedef _Float16 h2 __attribute__((ext_vector_type(2)));
typedef float f2 __attribute__((ext_vector_type(2)));

// pair-skewed float index: F(i) = i + 2*(i>>4); keeps (2p,2p+1) adjacent and
// 8B-aligned, pads 2 floats every 16 -> refill bank stride 18 (4-way, 1.58x)
__device__ __forceinline__ int F(int i) { return i + 2 * (i >> 4); }
__device__ __forceinline__ int pairF(int pp) { return 2 * pp + 2 * (pp >> 3); }

__device__ __forceinline__ f2 fma2(f2 a, f2 b, f2 c) {
  return __builtin_elementwise_fma(a, b, c);
}
__device__ __forceinline__ h2 pack_h2(float a, float b) {
  return __builtin_bit_cast(h2, __builtin_amdgcn_cvt_pkrtz(a, b));
}

// One block per (view, batch-half): 4 rows. Ramp filter (odd-d taps + center),
// scale by cosw, write PAIRED fp16: word[v][w][b] = (y[w][b], y[w+1][b]).
__global__ __launch_bounds__(256) void filt_kernel(
    const float* __restrict__ x, const float* __restrict__ filt,
    h2* __restrict__ sino2)
{
  __shared__ float xs[NBB * ROWSTRIDE];   // 29.6 KB; reused as ys after conv
  const int tid = threadIdx.x;
  const int v = blockIdx.x >> 1;
  const int bhalf = blockIdx.x & 1;

  // stage 4 rows (batches bhalf*4 ..+3) of view v, zero-padded, pair-skewed
  for (int b = 0; b < NBB; ++b) {
    const float* __restrict__ src = &x[((bhalf * NBB + b) * NVIEW + v) * DETN];
    for (int qq = tid; qq < XPAD2; qq += 256) {
      const int s = qq - 407;
      float val = 0.0f;
      if (s >= 0 && s < DETN) val = src[s];
      xs[b * ROWSTRIDE + F(qq)] = val;
    }
  }
  __syncthreads();

  const bool active = tid < NBB * TPR;   // 204 compute threads
  const int b = tid / TPR;
  const int t = tid - b * TPR;
  const int w0 = t * T;
  f2 acc2[8];   // acc2[k] = (y[w0+2k], y[w0+2k+1])

  if (active) {
    const float* __restrict__ xrow = &xs[b * ROWSTRIDE];
    const int P0 = 8 * t;     // base pair position
    f2 q16[16];               // ring: slot (s+k)&15 holds pair pos P0+s+k
#pragma unroll
    for (int k = 0; k < 16; ++k)
      q16[k] = *(const f2*)&xrow[pairF(P0 + k)];
#pragma unroll
    for (int k = 0; k < 8; ++k) acc2[k] = (f2){0.0f, 0.0f};

    // 408 even-index taps (odd d): 25 double-groups of 16 + tail 8
    for (int g = 0; g < 26; ++g) {
#pragma unroll
      for (int u = 0; u < 8; ++u) {
        const int s = 16 * g + u;
        const float fv = filt[2 * s];          // wave-uniform -> s_load
        const f2 fv2 = {fv, fv};
#pragma unroll
        for (int k = 0; k < 8; ++k)
          acc2[k] = fma2(q16[(u + k) & 15], fv2, acc2[k]);
        q16[u] = *(const f2*)&xrow[pairF(P0 + s + 16)];
      }
      if (g == 25) break;      // steps 400..407 done
#pragma unroll
      for (int u = 0; u < 8; ++u) {
        const int s = 16 * g + 8 + u;
        const float fv = filt[2 * s];
        const f2 fv2 = {fv, fv};
#pragma unroll
        for (int k = 0; k < 8; ++k)
          acc2[k] = fma2(q16[(8 + u + k) & 15], fv2, acc2[k]);
        q16[8 + u] = *(const f2*)&xrow[pairF(P0 + s + 16)];
      }
    }
    // center tap (odd float offset 407 -> scalar reads)
    const float fc = filt[407];
#pragma unroll
    for (int k = 0; k < 8; ++k) {
      acc2[k].x = fmaf(xrow[F(w0 + 2 * k + 407)], fc, acc2[k].x);
      acc2[k].y = fmaf(xrow[F(w0 + 2 * k + 408)], fc, acc2[k].y);
    }
    // fold cos-weight
#pragma unroll
    for (int k = 0; k < 8; ++k) {
      const float udx = (float)(w0 + 2 * k) - 407.5f;
      const float udy = (float)(w0 + 2 * k + 1) - 407.5f;
      acc2[k].x *= SID / sqrtf(SID * SID + udx * udx);
      acc2[k].y *= SID / sqrtf(SID * SID + udy * udy);
    }
  }
  __syncthreads();          // all xs reads done -> reuse as ys

  float* ys = xs;           // [NBB][DETN+1]
  if (active) {
#pragma unroll
    for (int k = 0; k < 8; ++k) {
      ys[b * (DETN + 1) + w0 + 2 * k] = acc2[k].x;
      ys[b * (DETN + 1) + w0 + 2 * k + 1] = acc2[k].y;
    }
    if (t == 0) ys[b * (DETN + 1) + DETN] = 0.0f;   // pad
  }
  __syncthreads();

  // pair-pack write: word idx = w*8 + bhalf*4 + bb  (16B contiguous per det)
  h2* dst = sino2 + (size_t)v * DETN * NB + bhalf * NBB;
  for (int idx = tid; idx < DETN * NBB; idx += 256) {
    const int w = idx >> 2;
    const int bb = idx & 3;
    h2 hp;
    hp[0] = (_Float16)ys[bb * (DETN + 1) + w];
    hp[1] = (_Float16)ys[bb * (DETN + 1) + w + 1];
    dst[w * 8 + bb] = hp;
  }
}

__device__ __forceinline__ float dot2acc(h2 w, unsigned int q, float acc) {
  return __builtin_amdgcn_fdot2(w, __builtin_bit_cast(h2, q), acc, false);
}

// 2 pixels (j, j+1) per thread. px1 reuses px0's 32B when both fall in the
// same pair-word det row (P~0.5); the px1 load is exec-masked -> fewer TCP
// lane-requests. px1 geometry derived from px0 via packed increments +
// one-term Newton reciprocal (rel err <= 2.2e-6).
__global__ __launch_bounds__(256, 4) void bp_kernel(
    const h2* __restrict__ sino2, float* __restrict__ out)
{
  __shared__ f2 cbp_t[VP], sbp_t[VP], csp_t[VP], ssp_t[VP];
  const int tid = threadIdx.x;
  const int v0 = blockIdx.z * VH;
  for (int it = tid; it < VP; it += 256) {
    float sA, cA, sB, cB;
    sincosf((float)(v0 + 2 * it) * DBETA, &sA, &cA);
    sincosf((float)(v0 + 2 * it + 1) * DBETA, &sB, &cB);
    cbp_t[it] = (f2){cA, cB};
    sbp_t[it] = (f2){sA, sB};
    csp_t[it] = (f2){SDD * cA, SDD * cB};
    ssp_t[it] = (f2){SDD * sA, SDD * sB};
  }
  __syncthreads();

  // wave = 16x8 px (8x8 lanes, 2 px in x per lane); block = 32x16 tile
  const int lane = tid & 63;
  const int wv = tid >> 6;
  const int j = (blockIdx.x << 5) + ((wv & 1) << 4) + ((lane & 7) << 1);
  const int i = (blockIdx.y << 4) + ((wv >> 1) << 3) + (lane >> 3);
  const float X = ((float)j - 255.5f) * PIXSZ;
  const float Y = -(((float)i - 255.5f) * PIXSZ);
  const f2 X2 = {X, X};
  const f2 Y2 = {Y, Y};
  const f2 nY2 = {-Y, -Y};
  const f2 SID2 = {SID, SID};
  const f2 C4075 = {407.5f, 407.5f};
  const f2 HALF2 = {0.5f, 0.5f};

  float acc0[NB], acc1[NB];
#pragma unroll
  for (int b = 0; b < NB; ++b) { acc0[b] = 0.0f; acc1[b] = 0.0f; }

  const char* pv = (const char*)sino2 + (size_t)v0 * DETN * NB * 4;
  constexpr int VSTRIDE = DETN * NB * 4;   // bytes per view (paired fp16)

  for (int it = 0; it < VP; ++it) {
    const f2 cb2 = cbp_t[it];
    const f2 sb2 = sbp_t[it];
    const f2 cs2 = csp_t[it];
    const f2 ss2 = ssp_t[it];

    // px0 geometry (2 views packed)
    const f2 num0 = fma2(Y2, ss2, X2 * cs2);            // SDD * xr
    const f2 L0 = fma2(nY2, cb2, fma2(X2, sb2, SID2));
    const f2 rL0 = {__builtin_amdgcn_rcpf(L0.x), __builtin_amdgcn_rcpf(L0.y)};
    const f2 tt0 = fma2(num0, rL0, C4075);              // in [97.5, 717.5]
    const f2 m0 = SID2 * rL0;
    const f2 w0v = m0 * m0;
    // px1 = px0 + (dx=0.5): num += 0.5*SDD*cb, L += 0.5*sb, Newton rcp
    const f2 hcs = HALF2 * cs2;
    const f2 hsb = HALF2 * sb2;
    const f2 rL0sq = rL0 * rL0;
    const f2 rL1 = fma2(-hsb, rL0sq, rL0);
    const f2 num1 = num0 + hcs;
    const f2 tt1 = fma2(num1, rL1, C4075);
    const f2 m1 = SID2 * rL1;
    const f2 w1v = m1 * m1;

    // ---- view A (lane .x) ----
    {
      const int rA = __float2int_rd(tt0.x);
      const float frA = tt0.x - (float)rA;
      const float a1A = w0v.x * frA;
      const h2 wA = pack_h2(w0v.x - a1A, a1A);
      const int rB = __float2int_rd(tt1.x);
      const float frB = tt1.x - (float)rB;
      const float a1B = w1v.x * frB;
      const h2 wB = pack_h2(w1v.x - a1B, a1B);

      const uint4* pa = (const uint4*)(pv + (rA << 5));
      const uint4 qa0 = pa[0], qa1 = pa[1];
      uint4 qb0 = qa0, qb1 = qa1;
      if (rB != rA) {                      // exec-masked: ~50% of lanes
        const uint4* pb = (const uint4*)(pv + (rB << 5));
        qb0 = pb[0]; qb1 = pb[1];
      }
      acc0[0] = dot2acc(wA, qa0.x, acc0[0]);
      acc0[1] = dot2acc(wA, qa0.y, acc0[1]);
      acc0[2] = dot2acc(wA, qa0.z, acc0[2]);
      acc0[3] = dot2acc(wA, qa0.w, acc0[3]);
      acc0[4] = dot2acc(wA, qa1.x, acc0[4]);
      acc0[5] = dot2acc(wA, qa1.y, acc0[5]);
      acc0[6] = dot2acc(wA, qa1.z, acc0[6]);
      acc0[7] = dot2acc(wA, qa1.w, acc0[7]);
      acc1[0] = dot2acc(wB, qb0.x, acc1[0]);
      acc1[1] = dot2acc(wB, qb0.y, acc1[1]);
      acc1[2] = dot2acc(wB, qb0.z, acc1[2]);
      acc1[3] = dot2acc(wB, qb0.w, acc1[3]);
      acc1[4] = dot2acc(wB, qb1.x, acc1[4]);
      acc1[5] = dot2acc(wB, qb1.y, acc1[5]);
      acc1[6] = dot2acc(wB, qb1.z, acc1[6]);
      acc1[7] = dot2acc(wB, qb1.w, acc1[7]);
    }
    // ---- view B (lane .y) ----
    {
      const int rA = __float2int_rd(tt0.y);
      const float frA = tt0.y - (float)rA;
      const float a1A = w0v.y * frA;
      const h2 wA = pack_h2(w0v.y - a1A, a1A);
      const int rB = __float2int_rd(tt1.y);
      const float frB = tt1.y - (float)rB;
      const float a1B = w1v.y * frB;
      const h2 wB = pack_h2(w1v.y - a1B, a1B);

      const uint4* pa = (const uint4*)(pv + VSTRIDE + (rA << 5));
      const uint4 qa0 = pa[0], qa1 = pa[1];
      uint4 qb0 = qa0, qb1 = qa1;
      if (rB != rA) {
        const uint4* pb = (const uint4*)(pv + VSTRIDE + (rB << 5));
        qb0 = pb[0]; qb1 = pb[1];
      }
      acc0[0] = dot2acc(wA, qa0.x, acc0[0]);
      acc0[1] = dot2acc(wA, qa0.y, acc0[1]);
      acc0[2] = dot2acc(wA, qa0.z, acc0[2]);
      acc0[3] = dot2acc(wA, qa0.w, acc0[3]);
      acc0[4] = dot2acc(wA, qa1.x, acc0[4]);
      acc0[5] = dot2acc(wA, qa1.y, acc0[5]);
      acc0[6] = dot2acc(wA, qa1.z, acc0[6]);
      acc0[7] = dot2acc(wA, qa1.w, acc0[7]);
      acc1[0] = dot2acc(wB, qb0.x, acc1[0]);
      acc1[1] = dot2acc(wB, qb0.y, acc1[1]);
      acc1[2] = dot2acc(wB, qb0.z, acc1[2]);
      acc1[3] = dot2acc(wB, qb0.w, acc1[3]);
      acc1[4] = dot2acc(wB, qb1.x, acc1[4]);
      acc1[5] = dot2acc(wB, qb1.y, acc1[5]);
      acc1[6] = dot2acc(wB, qb1.z, acc1[6]);
      acc1[7] = dot2acc(wB, qb1.w, acc1[7]);
    }

    pv += 2 * VSTRIDE;
  }

#pragma unroll
  for (int b = 0; b < NB; ++b) {
    atomicAdd(&out[(b * IMGN + i) * IMGN + j], acc0[b] * DBETA);
    atomicAdd(&out[(b * IMGN + i) * IMGN + j + 1], acc1[b] * DBETA);
  }
}

} // namespace

extern "C" void kernel_launch(void* const* d_in, const int* in_sizes, int n_in,
                              void* d_out, int out_size, void* d_ws, size_t ws_size,
                              hipStream_t stream) {
  const float* x = (const float*)d_in[0];
  const float* filt = (const float*)d_in[1];
  float* out = (float*)d_out;
  h2* sino2 = (h2*)d_ws;   // 720*816*8 paired-fp16 words = 18.8 MB

  (void)hipMemsetAsync(out, 0, (size_t)out_size * sizeof(float), stream);
  filt_kernel<<<NVIEW * 2, 256, 0, stream>>>(x, filt, sino2);
  bp_kernel<<<dim3(IMGN / 32, IMGN / 16, NSPLIT), 256, 0, stream>>>(sino2, out);
}

// Round 12
// 260.313 us; speedup vs baseline: 1.2074x; 1.2074x over previous
//
#include <hip/hip_runtime.h>
#include <math.h>

namespace {
constexpr int DETN = 816;
constexpr int NVIEW = 720;
constexpr int NB = 8;
constexpr int IMGN = 512;
constexpr float PIXSZ = 0.5f;
constexpr float SID = 750.0f;
constexpr float SDD = 1250.0f;
constexpr float DBETA = 6.28318530717958647692f / 720.0f;

constexpr int XPAD2 = 1648;      // 407 left zeros + 816 data + 425 right zeros
constexpr int T = 24;            // outputs per thread
constexpr int TPR = DETN / T;    // 34 threads per row
constexpr int ROWSTRIDE = 1852;  // > F(1647)=1851, even
constexpr int NBB = 4;           // batches per filter block
constexpr int FTH = 192;         // filter block threads

constexpr int NSPLIT = 2;
constexpr int VH = NVIEW / NSPLIT;   // 360 views per half
constexpr int VP = VH / 2;           // 180 view-pairs
constexpr int VQ = VH / 4;           // 90 view-quads

typedef _Float16 h2 __attribute__((ext_vector_type(2)));
typedef float f2 __attribute__((ext_vector_type(2)));

// pair-skewed float index: F(i) = i + 2*(i>>4); keeps (2p,2p+1) adjacent and
// 8B-aligned, pads 2 floats every 16 -> refill bank stride ~27 (no hot bank)
__device__ __forceinline__ int F(int i) { return i + 2 * (i >> 4); }
__device__ __forceinline__ int pairF(int pp) { return 2 * pp + 2 * (pp >> 3); }

__device__ __forceinline__ f2 fma2(f2 a, f2 b, f2 c) {
  return __builtin_elementwise_fma(a, b, c);
}
__device__ __forceinline__ h2 pack_h2(float a, float b) {
  return __builtin_bit_cast(h2, __builtin_amdgcn_cvt_pkrtz(a, b));
}

// One block per (view, batch-half): 4 rows, 34 threads x 24 outputs each.
// Ramp filter (odd-d taps + center), scale by cosw, write PAIRED fp16:
// word[v][w][b] = (y[w][b], y[w+1][b]).
// 16-deep register ring: slot (s+k)&15 holds pair P0+s+k (k=0..15); step s
// uses k=0..11 (12 pk_fma), refills slot s&15 with pair P0+s+16 (first used
// 5 steps later ~120 issue-cy) -> LDS latency hidden; LDS traffic 34/51 of T=16.
__global__ __launch_bounds__(FTH) void filt_kernel(
    const float* __restrict__ x, const float* __restrict__ filt,
    h2* __restrict__ sino2)
{
  __shared__ float xs[NBB * ROWSTRIDE];   // 29.6 KB; reused as ys after conv
  const int tid = threadIdx.x;
  const int v = blockIdx.x >> 1;
  const int bhalf = blockIdx.x & 1;

  // stage 4 rows (batches bhalf*4 ..+3) of view v, zero-padded, pair-skewed
  for (int b = 0; b < NBB; ++b) {
    const float* __restrict__ src = &x[((bhalf * NBB + b) * NVIEW + v) * DETN];
    for (int qq = tid; qq < XPAD2; qq += FTH) {
      const int s = qq - 407;
      float val = 0.0f;
      if (s >= 0 && s < DETN) val = src[s];
      xs[b * ROWSTRIDE + F(qq)] = val;
    }
  }
  __syncthreads();

  const bool active = tid < NBB * TPR;   // 136 compute threads
  const int b = tid / TPR;
  const int t = tid - b * TPR;
  const int w0 = t * T;
  f2 acc2[12];   // acc2[k] = (y[w0+2k], y[w0+2k+1])

  if (active) {
    const float* __restrict__ xrow = &xs[b * ROWSTRIDE];
    const int P0 = 12 * t;    // base pair position
    f2 q16[16];               // ring: slot (s+k)&15 holds pair pos P0+s+k
#pragma unroll
    for (int k = 0; k < 16; ++k)
      q16[k] = *(const f2*)&xrow[pairF(P0 + k)];
#pragma unroll
    for (int k = 0; k < 12; ++k) acc2[k] = (f2){0.0f, 0.0f};

    // 408 even-index taps (odd d): 25 double-groups of 16 + tail 8
    for (int g = 0; g < 26; ++g) {
#pragma unroll
      for (int u = 0; u < 8; ++u) {
        const int s = 16 * g + u;
        const float fv = filt[2 * s];          // wave-uniform -> s_load
        const f2 fv2 = {fv, fv};
#pragma unroll
        for (int k = 0; k < 12; ++k)
          acc2[k] = fma2(q16[(u + k) & 15], fv2, acc2[k]);
        q16[u] = *(const f2*)&xrow[pairF(P0 + s + 16)];
      }
      if (g == 25) break;      // steps 400..407 done
#pragma unroll
      for (int u = 0; u < 8; ++u) {
        const int s = 16 * g + 8 + u;
        const float fv = filt[2 * s];
        const f2 fv2 = {fv, fv};
#pragma unroll
        for (int k = 0; k < 12; ++k)
          acc2[k] = fma2(q16[(8 + u + k) & 15], fv2, acc2[k]);
        q16[8 + u] = *(const f2*)&xrow[pairF(P0 + s + 16)];
      }
    }
    // center tap (odd float offset 407 -> scalar reads)
    const float fc = filt[407];
#pragma unroll
    for (int k = 0; k < 12; ++k) {
      acc2[k].x = fmaf(xrow[F(w0 + 2 * k + 407)], fc, acc2[k].x);
      acc2[k].y = fmaf(xrow[F(w0 + 2 * k + 408)], fc, acc2[k].y);
    }
    // fold cos-weight
#pragma unroll
    for (int k = 0; k < 12; ++k) {
      const float udx = (float)(w0 + 2 * k) - 407.5f;
      const float udy = (float)(w0 + 2 * k + 1) - 407.5f;
      acc2[k].x *= SID / sqrtf(SID * SID + udx * udx);
      acc2[k].y *= SID / sqrtf(SID * SID + udy * udy);
    }
  }
  __syncthreads();          // all xs reads done -> reuse as ys

  float* ys = xs;           // [NBB][DETN+1]
  if (active) {
#pragma unroll
    for (int k = 0; k < 12; ++k) {
      ys[b * (DETN + 1) + w0 + 2 * k] = acc2[k].x;
      ys[b * (DETN + 1) + w0 + 2 * k + 1] = acc2[k].y;
    }
    if (t == 0) ys[b * (DETN + 1) + DETN] = 0.0f;   // pad
  }
  __syncthreads();

  // pair-pack write: word idx = w*8 + bhalf*4 + bb  (16B contiguous per det)
  h2* dst = sino2 + (size_t)v * DETN * NB + bhalf * NBB;
  for (int idx = tid; idx < DETN * NBB; idx += FTH) {
    const int w = idx >> 2;
    const int bb = idx & 3;
    h2 hp;
    hp[0] = (_Float16)ys[bb * (DETN + 1) + w];
    hp[1] = (_Float16)ys[bb * (DETN + 1) + w + 1];
    dst[w * 8 + bb] = hp;
  }
}

__device__ __forceinline__ float dot2acc(h2 w, unsigned int q, float acc) {
  return __builtin_amdgcn_fdot2(w, __builtin_bit_cast(h2, q), acc, false);
}

// 16x16-pixel blocks; 4-view unroll (8 independent dwordx4 in flight).
// (round-10 version: pinned at the TCP gather request-rate ceiling)
__global__ __launch_bounds__(256, 6) void bp_kernel(
    const h2* __restrict__ sino2, float* __restrict__ out)
{
  // per view-pair tables: (cos,cos), (sin,sin), SDD-scaled versions
  __shared__ f2 cbp_t[VP], sbp_t[VP], csp_t[VP], ssp_t[VP];
  const int tid = threadIdx.x;
  const int v0 = blockIdx.z * VH;
  for (int it = tid; it < VP; it += 256) {
    float sA, cA, sB, cB;
    sincosf((float)(v0 + 2 * it) * DBETA, &sA, &cA);
    sincosf((float)(v0 + 2 * it + 1) * DBETA, &sB, &cB);
    cbp_t[it] = (f2){cA, cB};
    sbp_t[it] = (f2){sA, sB};
    csp_t[it] = (f2){SDD * cA, SDD * cB};
    ssp_t[it] = (f2){SDD * sA, SDD * sB};
  }
  __syncthreads();

  // wave = 8x8 pixel patch; block = 16x16 tile
  const int lane = tid & 63;
  const int wv = tid >> 6;
  const int px = ((wv & 1) << 3) | (lane & 7);
  const int py = ((wv >> 1) << 3) | (lane >> 3);
  const int j = (blockIdx.x << 4) + px;
  const int i = (blockIdx.y << 4) + py;
  const float X = ((float)j - 255.5f) * PIXSZ;
  const float Y = -(((float)i - 255.5f) * PIXSZ);
  const f2 X2 = {X, X};
  const f2 Y2 = {Y, Y};
  const f2 nY2 = {-Y, -Y};
  const f2 SID2 = {SID, SID};
  const f2 C4075 = {407.5f, 407.5f};

  float acc[NB];
#pragma unroll
  for (int b = 0; b < NB; ++b) acc[b] = 0.0f;

  const char* pv = (const char*)sino2 + (size_t)v0 * DETN * NB * 4;
  constexpr int VSTRIDE = DETN * NB * 4;   // bytes per view (paired fp16)

  for (int qd = 0; qd < VQ; ++qd) {
    // ---- geometry for views 4qd..4qd+3 as two f2 pairs ----
    const f2 cb0 = cbp_t[2 * qd],     cb1 = cbp_t[2 * qd + 1];
    const f2 sb0 = sbp_t[2 * qd],     sb1 = sbp_t[2 * qd + 1];
    const f2 cs0 = csp_t[2 * qd],     cs1 = csp_t[2 * qd + 1];
    const f2 ss0 = ssp_t[2 * qd],     ss1 = ssp_t[2 * qd + 1];

    const f2 num0 = fma2(Y2, ss0, X2 * cs0);
    const f2 num1 = fma2(Y2, ss1, X2 * cs1);
    const f2 L0 = fma2(nY2, cb0, fma2(X2, sb0, SID2));
    const f2 L1 = fma2(nY2, cb1, fma2(X2, sb1, SID2));
    const f2 rL0 = {__builtin_amdgcn_rcpf(L0.x), __builtin_amdgcn_rcpf(L0.y)};
    const f2 rL1 = {__builtin_amdgcn_rcpf(L1.x), __builtin_amdgcn_rcpf(L1.y)};
    const f2 tt0 = fma2(num0, rL0, C4075);   // t in [97.5, 717.5] -> no clamp
    const f2 tt1 = fma2(num1, rL1, C4075);
    const f2 m0 = SID2 * rL0, m1 = SID2 * rL1;
    const f2 w0 = m0 * m0, w1 = m1 * m1;
    const float iA = floorf(tt0.x), iB = floorf(tt0.y);
    const float iC = floorf(tt1.x), iD = floorf(tt1.y);
    const int i0A = (int)iA, i0B = (int)iB, i0C = (int)iC, i0D = (int)iD;
    const f2 fr0 = tt0 - (f2){iA, iB};
    const f2 fr1 = tt1 - (f2){iC, iD};
    const f2 a1p0 = w0 * fr0, a1p1 = w1 * fr1;
    const f2 a0p0 = w0 - a1p0, a0p1 = w1 - a1p1;
    const h2 wpA = pack_h2(a0p0.x, a1p0.x);
    const h2 wpB = pack_h2(a0p0.y, a1p0.y);
    const h2 wpC = pack_h2(a0p1.x, a1p1.x);
    const h2 wpD = pack_h2(a0p1.y, a1p1.y);

    // ---- 8 independent dwordx4 gathers ----
    const uint4* pA = (const uint4*)(pv + (i0A << 5));
    const uint4* pB = (const uint4*)(pv + VSTRIDE + (i0B << 5));
    const uint4* pC = (const uint4*)(pv + 2 * VSTRIDE + (i0C << 5));
    const uint4* pD = (const uint4*)(pv + 3 * VSTRIDE + (i0D << 5));
    const uint4 qA0 = pA[0], qA1 = pA[1];
    const uint4 qB0 = pB[0], qB1 = pB[1];
    const uint4 qC0 = pC[0], qC1 = pC[1];
    const uint4 qD0 = pD[0], qD1 = pD[1];

    acc[0] = dot2acc(wpA, qA0.x, acc[0]);
    acc[1] = dot2acc(wpA, qA0.y, acc[1]);
    acc[2] = dot2acc(wpA, qA0.z, acc[2]);
    acc[3] = dot2acc(wpA, qA0.w, acc[3]);
    acc[4] = dot2acc(wpA, qA1.x, acc[4]);
    acc[5] = dot2acc(wpA, qA1.y, acc[5]);
    acc[6] = dot2acc(wpA, qA1.z, acc[6]);
    acc[7] = dot2acc(wpA, qA1.w, acc[7]);

    acc[0] = dot2acc(wpB, qB0.x, acc[0]);
    acc[1] = dot2acc(wpB, qB0.y, acc[1]);
    acc[2] = dot2acc(wpB, qB0.z, acc[2]);
    acc[3] = dot2acc(wpB, qB0.w, acc[3]);
    acc[4] = dot2acc(wpB, qB1.x, acc[4]);
    acc[5] = dot2acc(wpB, qB1.y, acc[5]);
    acc[6] = dot2acc(wpB, qB1.z, acc[6]);
    acc[7] = dot2acc(wpB, qB1.w, acc[7]);

    acc[0] = dot2acc(wpC, qC0.x, acc[0]);
    acc[1] = dot2acc(wpC, qC0.y, acc[1]);
    acc[2] = dot2acc(wpC, qC0.z, acc[2]);
    acc[3] = dot2acc(wpC, qC0.w, acc[3]);
    acc[4] = dot2acc(wpC, qC1.x, acc[4]);
    acc[5] = dot2acc(wpC, qC1.y, acc[5]);
    acc[6] = dot2acc(wpC, qC1.z, acc[6]);
    acc[7] = dot2acc(wpC, qC1.w, acc[7]);

    acc[0] = dot2acc(wpD, qD0.x, acc[0]);
    acc[1] = dot2acc(wpD, qD0.y, acc[1]);
    acc[2] = dot2acc(wpD, qD0.z, acc[2]);
    acc[3] = dot2acc(wpD, qD0.w, acc[3]);
    acc[4] = dot2acc(wpD, qD1.x, acc[4]);
    acc[5] = dot2acc(wpD, qD1.y, acc[5]);
    acc[6] = dot2acc(wpD, qD1.z, acc[6]);
    acc[7] = dot2acc(wpD, qD1.w, acc[7]);

    pv += 4 * VSTRIDE;
  }

#pragma unroll
  for (int b = 0; b < NB; ++b)
    atomicAdd(&out[(b * IMGN + i) * IMGN + j], acc[b] * DBETA);
}

} // namespace

extern "C" void kernel_launch(void* const* d_in, const int* in_sizes, int n_in,
                              void* d_out, int out_size, void* d_ws, size_t ws_size,
                              hipStream_t stream) {
  const float* x = (const float*)d_in[0];
  const float* filt = (const float*)d_in[1];
  float* out = (float*)d_out;
  h2* sino2 = (h2*)d_ws;   // 720*816*8 paired-fp16 words = 18.8 MB

  (void)hipMemsetAsync(out, 0, (size_t)out_size * sizeof(float), stream);
  filt_kernel<<<NVIEW * 2, FTH, 0, stream>>>(x, filt, sino2);
  bp_kernel<<<dim3(IMGN / 16, IMGN / 16, NSPLIT), 256, 0, stream>>>(sino2, out);
}

// Round 13
// 250.219 us; speedup vs baseline: 1.2561x; 1.0403x over previous
//
#include <hip/hip_runtime.h>
#include <math.h>

namespace {
constexpr int DETN = 816;
constexpr int NVIEW = 720;
constexpr int NB = 8;
constexpr int IMGN = 512;
constexpr float PIXSZ = 0.5f;
constexpr float SID = 750.0f;
constexpr float SDD = 1250.0f;
constexpr float DBETA = 6.28318530717958647692f / 720.0f;

constexpr int XPAD2 = 1648;      // 407 left zeros + 816 data + 425 right zeros
constexpr int T = 16;            // outputs per thread
constexpr int TPR = DETN / T;    // 51 threads per row
constexpr int ROWSTRIDE = 1852;  // > F(1647)=1851, even
constexpr int NBB = 4;           // batches per filter block

constexpr int NSPLIT = 2;
constexpr int VH = NVIEW / NSPLIT;   // 360 views per half
constexpr int VP = VH / 2;           // 180 view-pairs
constexpr int VQ = VH / 4;           // 90 view-quads

typedef _Float16 h2 __attribute__((ext_vector_type(2)));
typedef float f2 __attribute__((ext_vector_type(2)));

// pair-skewed float index: F(i) = i + 2*(i>>4); keeps (2p,2p+1) adjacent and
// 8B-aligned, pads 2 floats every 16 -> refill bank stride 18 (4-way, 1.58x)
__device__ __forceinline__ int F(int i) { return i + 2 * (i >> 4); }
__device__ __forceinline__ int pairF(int pp) { return 2 * pp + 2 * (pp >> 3); }

__device__ __forceinline__ f2 fma2(f2 a, f2 b, f2 c) {
  return __builtin_elementwise_fma(a, b, c);
}
__device__ __forceinline__ h2 pack_h2(float a, float b) {
  return __builtin_bit_cast(h2, __builtin_amdgcn_cvt_pkrtz(a, b));
}

// One block per (view, batch-half): 4 rows. Ramp filter (odd-d taps + center),
// scale by cosw, write PAIRED fp16: word[v][w][b] = (y[w][b], y[w+1][b]).
// 16-deep register ring: slot (s+k)&15 holds pair P0+s+k; refill of pair
// P0+s+16 lands in the slot vacated at step s and is first used 9 steps
// later (~144 issue-cycles) -> LDS latency fully hidden by ILP.
__global__ __launch_bounds__(256) void filt_kernel(
    const float* __restrict__ x, const float* __restrict__ filt,
    h2* __restrict__ sino2)
{
  __shared__ float xs[NBB * ROWSTRIDE];   // 29.6 KB; reused as ys after conv
  const int tid = threadIdx.x;
  const int v = blockIdx.x >> 1;
  const int bhalf = blockIdx.x & 1;

  // stage 4 rows (batches bhalf*4 ..+3) of view v, zero-padded, pair-skewed
  for (int b = 0; b < NBB; ++b) {
    const float* __restrict__ src = &x[((bhalf * NBB + b) * NVIEW + v) * DETN];
    for (int qq = tid; qq < XPAD2; qq += 256) {
      const int s = qq - 407;
      float val = 0.0f;
      if (s >= 0 && s < DETN) val = src[s];
      xs[b * ROWSTRIDE + F(qq)] = val;
    }
  }
  __syncthreads();

  const bool active = tid < NBB * TPR;   // 204 compute threads
  const int b = tid / TPR;
  const int t = tid - b * TPR;
  const int w0 = t * T;
  f2 acc2[8];   // acc2[k] = (y[w0+2k], y[w0+2k+1])

  if (active) {
    const float* __restrict__ xrow = &xs[b * ROWSTRIDE];
    const int P0 = 8 * t;     // base pair position
    f2 q16[16];               // ring: slot (s+k)&15 holds pair pos P0+s+k
#pragma unroll
    for (int k = 0; k < 16; ++k)
      q16[k] = *(const f2*)&xrow[pairF(P0 + k)];
#pragma unroll
    for (int k = 0; k < 8; ++k) acc2[k] = (f2){0.0f, 0.0f};

    // 408 even-index taps (odd d): 25 double-groups of 16 + tail 8
    for (int g = 0; g < 26; ++g) {
#pragma unroll
      for (int u = 0; u < 8; ++u) {
        const int s = 16 * g + u;
        const float fv = filt[2 * s];          // wave-uniform -> s_load
        const f2 fv2 = {fv, fv};
#pragma unroll
        for (int k = 0; k < 8; ++k)
          acc2[k] = fma2(q16[(u + k) & 15], fv2, acc2[k]);
        q16[u] = *(const f2*)&xrow[pairF(P0 + s + 16)];
      }
      if (g == 25) break;      // steps 400..407 done
#pragma unroll
      for (int u = 0; u < 8; ++u) {
        const int s = 16 * g + 8 + u;
        const float fv = filt[2 * s];
        const f2 fv2 = {fv, fv};
#pragma unroll
        for (int k = 0; k < 8; ++k)
          acc2[k] = fma2(q16[(8 + u + k) & 15], fv2, acc2[k]);
        q16[8 + u] = *(const f2*)&xrow[pairF(P0 + s + 16)];
      }
    }
    // center tap (odd float offset 407 -> scalar reads)
    const float fc = filt[407];
#pragma unroll
    for (int k = 0; k < 8; ++k) {
      acc2[k].x = fmaf(xrow[F(w0 + 2 * k + 407)], fc, acc2[k].x);
      acc2[k].y = fmaf(xrow[F(w0 + 2 * k + 408)], fc, acc2[k].y);
    }
    // fold cos-weight
#pragma unroll
    for (int k = 0; k < 8; ++k) {
      const float udx = (float)(w0 + 2 * k) - 407.5f;
      const float udy = (float)(w0 + 2 * k + 1) - 407.5f;
      acc2[k].x *= SID / sqrtf(SID * SID + udx * udx);
      acc2[k].y *= SID / sqrtf(SID * SID + udy * udy);
    }
  }
  __syncthreads();          // all xs reads done -> reuse as ys

  float* ys = xs;           // [NBB][DETN+1]
  if (active) {
#pragma unroll
    for (int k = 0; k < 8; ++k) {
      ys[b * (DETN + 1) + w0 + 2 * k] = acc2[k].x;
      ys[b * (DETN + 1) + w0 + 2 * k + 1] = acc2[k].y;
    }
    if (t == 0) ys[b * (DETN + 1) + DETN] = 0.0f;   // pad
  }
  __syncthreads();

  // pair-pack write: word idx = w*8 + bhalf*4 + bb  (16B contiguous per det)
  h2* dst = sino2 + (size_t)v * DETN * NB + bhalf * NBB;
  for (int idx = tid; idx < DETN * NBB; idx += 256) {
    const int w = idx >> 2;
    const int bb = idx & 3;
    h2 hp;
    hp[0] = (_Float16)ys[bb * (DETN + 1) + w];
    hp[1] = (_Float16)ys[bb * (DETN + 1) + w + 1];
    dst[w * 8 + bb] = hp;
  }
}

__device__ __forceinline__ float dot2acc(h2 w, unsigned int q, float acc) {
  return __builtin_amdgcn_fdot2(w, __builtin_bit_cast(h2, q), acc, false);
}

// 16x16-pixel blocks; 4-view unroll (8 independent dwordx4 in flight).
// Pinned at the TCP gather request-rate ceiling (~79% of the 154 us
// 4-lane-req/cy/CU floor); occupancy x1.6, MLP x2, L1-shape and
// request-sharing variants all landed at 195 +/- 1 us or worse.
__global__ __launch_bounds__(256, 6) void bp_kernel(
    const h2* __restrict__ sino2, float* __restrict__ out)
{
  // per view-pair tables: (cos,cos), (sin,sin), SDD-scaled versions
  __shared__ f2 cbp_t[VP], sbp_t[VP], csp_t[VP], ssp_t[VP];
  const int tid = threadIdx.x;
  const int v0 = blockIdx.z * VH;
  for (int it = tid; it < VP; it += 256) {
    float sA, cA, sB, cB;
    sincosf((float)(v0 + 2 * it) * DBETA, &sA, &cA);
    sincosf((float)(v0 + 2 * it + 1) * DBETA, &sB, &cB);
    cbp_t[it] = (f2){cA, cB};
    sbp_t[it] = (f2){sA, sB};
    csp_t[it] = (f2){SDD * cA, SDD * cB};
    ssp_t[it] = (f2){SDD * sA, SDD * sB};
  }
  __syncthreads();

  // wave = 8x8 pixel patch; block = 16x16 tile
  const int lane = tid & 63;
  const int wv = tid >> 6;
  const int px = ((wv & 1) << 3) | (lane & 7);
  const int py = ((wv >> 1) << 3) | (lane >> 3);
  const int j = (blockIdx.x << 4) + px;
  const int i = (blockIdx.y << 4) + py;
  const float X = ((float)j - 255.5f) * PIXSZ;
  const float Y = -(((float)i - 255.5f) * PIXSZ);
  const f2 X2 = {X, X};
  const f2 Y2 = {Y, Y};
  const f2 nY2 = {-Y, -Y};
  const f2 SID2 = {SID, SID};
  const f2 C4075 = {407.5f, 407.5f};

  float acc[NB];
#pragma unroll
  for (int b = 0; b < NB; ++b) acc[b] = 0.0f;

  const char* pv = (const char*)sino2 + (size_t)v0 * DETN * NB * 4;
  constexpr int VSTRIDE = DETN * NB * 4;   // bytes per view (paired fp16)

  for (int qd = 0; qd < VQ; ++qd) {
    // ---- geometry for views 4qd..4qd+3 as two f2 pairs ----
    const f2 cb0 = cbp_t[2 * qd],     cb1 = cbp_t[2 * qd + 1];
    const f2 sb0 = sbp_t[2 * qd],     sb1 = sbp_t[2 * qd + 1];
    const f2 cs0 = csp_t[2 * qd],     cs1 = csp_t[2 * qd + 1];
    const f2 ss0 = ssp_t[2 * qd],     ss1 = ssp_t[2 * qd + 1];

    const f2 num0 = fma2(Y2, ss0, X2 * cs0);
    const f2 num1 = fma2(Y2, ss1, X2 * cs1);
    const f2 L0 = fma2(nY2, cb0, fma2(X2, sb0, SID2));
    const f2 L1 = fma2(nY2, cb1, fma2(X2, sb1, SID2));
    const f2 rL0 = {__builtin_amdgcn_rcpf(L0.x), __builtin_amdgcn_rcpf(L0.y)};
    const f2 rL1 = {__builtin_amdgcn_rcpf(L1.x), __builtin_amdgcn_rcpf(L1.y)};
    const f2 tt0 = fma2(num0, rL0, C4075);   // t in [97.5, 717.5] -> no clamp
    const f2 tt1 = fma2(num1, rL1, C4075);
    const f2 m0 = SID2 * rL0, m1 = SID2 * rL1;
    const f2 w0 = m0 * m0, w1 = m1 * m1;
    const float iA = floorf(tt0.x), iB = floorf(tt0.y);
    const float iC = floorf(tt1.x), iD = floorf(tt1.y);
    const int i0A = (int)iA, i0B = (int)iB, i0C = (int)iC, i0D = (int)iD;
    const f2 fr0 = tt0 - (f2){iA, iB};
    const f2 fr1 = tt1 - (f2){iC, iD};
    const f2 a1p0 = w0 * fr0, a1p1 = w1 * fr1;
    const f2 a0p0 = w0 - a1p0, a0p1 = w1 - a1p1;
    const h2 wpA = pack_h2(a0p0.x, a1p0.x);
    const h2 wpB = pack_h2(a0p0.y, a1p0.y);
    const h2 wpC = pack_h2(a0p1.x, a1p1.x);
    const h2 wpD = pack_h2(a0p1.y, a1p1.y);

    // ---- 8 independent dwordx4 gathers ----
    const uint4* pA = (const uint4*)(pv + (i0A << 5));
    const uint4* pB = (const uint4*)(pv + VSTRIDE + (i0B << 5));
    const uint4* pC = (const uint4*)(pv + 2 * VSTRIDE + (i0C << 5));
    const uint4* pD = (const uint4*)(pv + 3 * VSTRIDE + (i0D << 5));
    const uint4 qA0 = pA[0], qA1 = pA[1];
    const uint4 qB0 = pB[0], qB1 = pB[1];
    const uint4 qC0 = pC[0], qC1 = pC[1];
    const uint4 qD0 = pD[0], qD1 = pD[1];

    acc[0] = dot2acc(wpA, qA0.x, acc[0]);
    acc[1] = dot2acc(wpA, qA0.y, acc[1]);
    acc[2] = dot2acc(wpA, qA0.z, acc[2]);
    acc[3] = dot2acc(wpA, qA0.w, acc[3]);
    acc[4] = dot2acc(wpA, qA1.x, acc[4]);
    acc[5] = dot2acc(wpA, qA1.y, acc[5]);
    acc[6] = dot2acc(wpA, qA1.z, acc[6]);
    acc[7] = dot2acc(wpA, qA1.w, acc[7]);

    acc[0] = dot2acc(wpB, qB0.x, acc[0]);
    acc[1] = dot2acc(wpB, qB0.y, acc[1]);
    acc[2] = dot2acc(wpB, qB0.z, acc[2]);
    acc[3] = dot2acc(wpB, qB0.w, acc[3]);
    acc[4] = dot2acc(wpB, qB1.x, acc[4]);
    acc[5] = dot2acc(wpB, qB1.y, acc[5]);
    acc[6] = dot2acc(wpB, qB1.z, acc[6]);
    acc[7] = dot2acc(wpB, qB1.w, acc[7]);

    acc[0] = dot2acc(wpC, qC0.x, acc[0]);
    acc[1] = dot2acc(wpC, qC0.y, acc[1]);
    acc[2] = dot2acc(wpC, qC0.z, acc[2]);
    acc[3] = dot2acc(wpC, qC0.w, acc[3]);
    acc[4] = dot2acc(wpC, qC1.x, acc[4]);
    acc[5] = dot2acc(wpC, qC1.y, acc[5]);
    acc[6] = dot2acc(wpC, qC1.z, acc[6]);
    acc[7] = dot2acc(wpC, qC1.w, acc[7]);

    acc[0] = dot2acc(wpD, qD0.x, acc[0]);
    acc[1] = dot2acc(wpD, qD0.y, acc[1]);
    acc[2] = dot2acc(wpD, qD0.z, acc[2]);
    acc[3] = dot2acc(wpD, qD0.w, acc[3]);
    acc[4] = dot2acc(wpD, qD1.x, acc[4]);
    acc[5] = dot2acc(wpD, qD1.y, acc[5]);
    acc[6] = dot2acc(wpD, qD1.z, acc[6]);
    acc[7] = dot2acc(wpD, qD1.w, acc[7]);

    pv += 4 * VSTRIDE;
  }

#pragma unroll
  for (int b = 0; b < NB; ++b)
    atomicAdd(&out[(b * IMGN + i) * IMGN + j], acc[b] * DBETA);
}

} // namespace

extern "C" void kernel_launch(void* const* d_in, const int* in_sizes, int n_in,
                              void* d_out, int out_size, void* d_ws, size_t ws_size,
                              hipStream_t stream) {
  const float* x = (const float*)d_in[0];
  const float* filt = (const float*)d_in[1];
  float* out = (float*)d_out;
  h2* sino2 = (h2*)d_ws;   // 720*816*8 paired-fp16 words = 18.8 MB

  (void)hipMemsetAsync(out, 0, (size_t)out_size * sizeof(float), stream);
  filt_kernel<<<NVIEW * 2, 256, 0, stream>>>(x, filt, sino2);
  bp_kernel<<<dim3(IMGN / 16, IMGN / 16, NSPLIT), 256, 0, stream>>>(sino2, out);
}